// Round 5
// baseline (1896.944 us; speedup 1.0000x reference)
//
#include <hip/hip_runtime.h>

#define NEG_SLOPE 0.01f
#define EPT 8       // edges per thread in bucket kernel
#define BCAP 3072   // bucket capacity (mean 2048, sigma ~45 -> 22 sigma margin)

static __device__ __forceinline__ float lrelu(float v) {
    return v >= 0.0f ? v : NEG_SLOPE * v;
}

// bf16 pack/unpack (RNE)
static __device__ __forceinline__ unsigned pack_bf16(float a, float b) {
    unsigned ua = __float_as_uint(a);
    unsigned ub = __float_as_uint(b);
    ua = (ua + 0x7FFFu + ((ua >> 16) & 1u)) >> 16;
    ub = (ub + 0x7FFFu + ((ub >> 16) & 1u)) >> 16;
    return ua | (ub << 16);
}
static __device__ __forceinline__ float bflo(unsigned u) { return __uint_as_float(u << 16); }
static __device__ __forceinline__ float bfhi(unsigned u) { return __uint_as_float(u & 0xFFFF0000u); }

// ---------------- bucket edges by destination graph ----------------
// entry = (src << 7) | (dst & 127); bucket = dst >> 7.
// Appends to a bucket are sequential -> cache lines fill fully (low write amp).
__global__ void k_bucket(const int* __restrict__ edge, int E, int* bcnt, int* buckets) {
    int t = blockIdx.x * blockDim.x + threadIdx.x;
    int base = t * EPT;
    if (base + EPT <= E) {
        int4 sa = *(const int4*)&edge[base];
        int4 sb = *(const int4*)&edge[base + 4];
        int4 da = *(const int4*)&edge[E + base];
        int4 db = *(const int4*)&edge[E + base + 4];
        int g0 = da.x >> 7, g1 = da.y >> 7, g2 = da.z >> 7, g3 = da.w >> 7;
        int g4 = db.x >> 7, g5 = db.y >> 7, g6 = db.z >> 7, g7 = db.w >> 7;
        int e0 = (sa.x << 7) | (da.x & 127);
        int e1 = (sa.y << 7) | (da.y & 127);
        int e2 = (sa.z << 7) | (da.z & 127);
        int e3 = (sa.w << 7) | (da.w & 127);
        int e4 = (sb.x << 7) | (db.x & 127);
        int e5 = (sb.y << 7) | (db.y & 127);
        int e6 = (sb.z << 7) | (db.z & 127);
        int e7 = (sb.w << 7) | (db.w & 127);
        int p0 = atomicAdd(&bcnt[g0], 1);
        int p1 = atomicAdd(&bcnt[g1], 1);
        int p2 = atomicAdd(&bcnt[g2], 1);
        int p3 = atomicAdd(&bcnt[g3], 1);
        int p4 = atomicAdd(&bcnt[g4], 1);
        int p5 = atomicAdd(&bcnt[g5], 1);
        int p6 = atomicAdd(&bcnt[g6], 1);
        int p7 = atomicAdd(&bcnt[g7], 1);
        if (p0 < BCAP) buckets[g0 * BCAP + p0] = e0;
        if (p1 < BCAP) buckets[g1 * BCAP + p1] = e1;
        if (p2 < BCAP) buckets[g2 * BCAP + p2] = e2;
        if (p3 < BCAP) buckets[g3 * BCAP + p3] = e3;
        if (p4 < BCAP) buckets[g4 * BCAP + p4] = e4;
        if (p5 < BCAP) buckets[g5 * BCAP + p5] = e5;
        if (p6 < BCAP) buckets[g6 * BCAP + p6] = e6;
        if (p7 < BCAP) buckets[g7 * BCAP + p7] = e7;
    } else {
        for (int i = base; i < E; ++i) {
            int s = edge[i], d = edge[E + i];
            int g = d >> 7;
            int p = atomicAdd(&bcnt[g], 1);
            if (p < BCAP) buckets[g * BCAP + p] = (s << 7) | (d & 127);
        }
    }
}

// ---------------- per-graph degree histogram -> dinv ----------------
__global__ __launch_bounds__(256) void k_deg(const int* __restrict__ buckets,
                                             const int* __restrict__ bcnt,
                                             float* __restrict__ dinv) {
    __shared__ int c[128];
    int g = blockIdx.x, tid = threadIdx.x;
    if (tid < 128) c[tid] = 0;
    __syncthreads();
    int m = min(bcnt[g], BCAP);
    const int* bk = &buckets[g * BCAP];
    for (int i = tid; i < m; i += 256) atomicAdd(&c[bk[i] & 127], 1);
    __syncthreads();
    if (tid < 128) dinv[g * 128 + tid] = rsqrtf((float)(c[tid] + 1));  // +1 self loop
}

// ---------------- h = x @ W  (fp32 compute, bf16 out; word c = feats (c, c+64)) ----
#define BM 64
#define BK 32
__global__ __launch_bounds__(256) void k_gemm(const float* __restrict__ x,
                                              const float* __restrict__ W,
                                              unsigned* __restrict__ h2) {
    __shared__ float Xs[BM][BK + 4];
    __shared__ float Ws[BK][128];
    int tid = threadIdx.x;
    int tx = tid & 15;
    int ty = tid >> 4;
    long r0 = (long)blockIdx.x * BM;

    float acc[4][8];
#pragma unroll
    for (int j = 0; j < 4; ++j)
#pragma unroll
        for (int c = 0; c < 8; ++c) acc[j][c] = 0.0f;

    for (int k0 = 0; k0 < 128; k0 += BK) {
#pragma unroll
        for (int it = 0; it < 2; ++it) {
            int i = tid + it * 256;
            int row = i >> 3;
            int kq = i & 7;
            float4 v = *(const float4*)&x[(r0 + row) * 128 + k0 + kq * 4];
            *(float4*)&Xs[row][kq * 4] = v;
        }
#pragma unroll
        for (int it = 0; it < 4; ++it) {
            int i = tid + it * 256;
            int kk = i >> 5;
            int cq = i & 31;
            *(float4*)&Ws[kk][cq * 4] = *(const float4*)&W[(k0 + kk) * 128 + cq * 4];
        }
        __syncthreads();

#pragma unroll
        for (int k = 0; k < BK; k += 4) {
            float4 xf[4];
#pragma unroll
            for (int j = 0; j < 4; ++j) xf[j] = *(const float4*)&Xs[ty * 4 + j][k];
#pragma unroll
            for (int kk = 0; kk < 4; ++kk) {
                float4 wa = *(const float4*)&Ws[k + kk][tx * 4];
                float4 wb = *(const float4*)&Ws[k + kk][tx * 4 + 64];
#pragma unroll
                for (int j = 0; j < 4; ++j) {
                    float xs = ((const float*)&xf[j])[kk];
                    acc[j][0] += xs * wa.x;
                    acc[j][1] += xs * wa.y;
                    acc[j][2] += xs * wa.z;
                    acc[j][3] += xs * wa.w;
                    acc[j][4] += xs * wb.x;
                    acc[j][5] += xs * wb.y;
                    acc[j][6] += xs * wb.z;
                    acc[j][7] += xs * wb.w;
                }
            }
        }
        __syncthreads();
    }
    // word c holds feats (c, c+64): acc[j][k] is col tx*4+k, acc[j][k+4] is col tx*4+k+64
#pragma unroll
    for (int j = 0; j < 4; ++j) {
        long r = r0 + ty * 4 + j;
        uint4 pw;
        pw.x = pack_bf16(acc[j][0], acc[j][4]);
        pw.y = pack_bf16(acc[j][1], acc[j][5]);
        pw.z = pack_bf16(acc[j][2], acc[j][6]);
        pw.w = pack_bf16(acc[j][3], acc[j][7]);
        *(uint4*)&h2[r * 64 + tx * 4] = pw;
    }
}

// ---------------- aggregation: one block per graph, LDS accumulator ----------------
// acc[128 nodes][128 feats] fp32 in dynamic LDS (64KB) + red[8][128] (4KB).
// Per edge: 64 lanes gather h2[src] row (256B), ds_add_f32 into acc[dstlocal].
#define AGG_LDS ((128 * 128 + 8 * 128) * 4)
__global__ __launch_bounds__(512) void k_aggr(const unsigned* __restrict__ h2,
                                              const int* __restrict__ buckets,
                                              const int* __restrict__ bcnt,
                                              const float* __restrict__ dinv,
                                              const float* __restrict__ bias,
                                              float* __restrict__ pooled) {
    extern __shared__ float acc[];          // [128][128]
    float* red = acc + 128 * 128;           // [8][128]
    int wave = threadIdx.x >> 6;
    int lane = threadIdx.x & 63;
    int g = blockIdx.x;

    // zero acc
    for (int i = threadIdx.x; i < 128 * 32; i += 512)
        ((float4*)acc)[i] = make_float4(0.f, 0.f, 0.f, 0.f);
    __syncthreads();

    int m = min(bcnt[g], BCAP);
    const int* bk = &buckets[g * BCAP];
    const float* dloc = &dinv[g * 128];

    // contiguous chunk per wave
    int per = (m + 7) >> 3;
    int s0 = wave * per;
    int s1 = min(m, s0 + per);

    for (int basei = s0; basei < s1; basei += 64) {
        int mb = min(64, s1 - basei);
        int entry = 0;
        float we = 0.0f;
        if (lane < mb) {
            entry = bk[basei + lane];
            we = dinv[entry >> 7] * dloc[entry & 127];
        }
        int full = mb & ~3;
        for (int j = 0; j < full; j += 4) {
            int t0 = __shfl(entry, j);
            int t1 = __shfl(entry, j + 1);
            int t2 = __shfl(entry, j + 2);
            int t3 = __shfl(entry, j + 3);
            float w0 = __shfl(we, j);
            float w1 = __shfl(we, j + 1);
            float w2 = __shfl(we, j + 2);
            float w3 = __shfl(we, j + 3);
            unsigned u0 = h2[(size_t)(t0 >> 7) * 64 + lane];
            unsigned u1 = h2[(size_t)(t1 >> 7) * 64 + lane];
            unsigned u2 = h2[(size_t)(t2 >> 7) * 64 + lane];
            unsigned u3 = h2[(size_t)(t3 >> 7) * 64 + lane];
            int d0 = (t0 & 127) * 128, d1 = (t1 & 127) * 128;
            int d2 = (t2 & 127) * 128, d3 = (t3 & 127) * 128;
            atomicAdd(&acc[d0 + lane],      bflo(u0) * w0);
            atomicAdd(&acc[d0 + lane + 64], bfhi(u0) * w0);
            atomicAdd(&acc[d1 + lane],      bflo(u1) * w1);
            atomicAdd(&acc[d1 + lane + 64], bfhi(u1) * w1);
            atomicAdd(&acc[d2 + lane],      bflo(u2) * w2);
            atomicAdd(&acc[d2 + lane + 64], bfhi(u2) * w2);
            atomicAdd(&acc[d3 + lane],      bflo(u3) * w3);
            atomicAdd(&acc[d3 + lane + 64], bfhi(u3) * w3);
        }
        for (int j = full; j < mb; ++j) {
            int t0 = __shfl(entry, j);
            float w0 = __shfl(we, j);
            unsigned u0 = h2[(size_t)(t0 >> 7) * 64 + lane];
            int d0 = (t0 & 127) * 128;
            atomicAdd(&acc[d0 + lane],      bflo(u0) * w0);
            atomicAdd(&acc[d0 + lane + 64], bfhi(u0) * w0);
        }
    }
    __syncthreads();

    // epilogue: self loop + bias + lrelu + pool; wave handles 16 nodes
    float bx = bias[lane], by = bias[lane + 64];
    float sx = 0.0f, sy = 0.0f;
#pragma unroll
    for (int t = 0; t < 16; ++t) {
        int d = wave * 16 + t;
        int v = g * 128 + d;
        float dv = dloc[d];
        float dv2 = dv * dv;
        unsigned self = h2[(size_t)v * 64 + lane];
        sx += lrelu(acc[d * 128 + lane]      + bflo(self) * dv2 + bx);
        sy += lrelu(acc[d * 128 + lane + 64] + bfhi(self) * dv2 + by);
    }
    red[wave * 128 + lane]      = sx;
    red[wave * 128 + lane + 64] = sy;
    __syncthreads();
    if (wave == 0) {
        float tx = 0.0f, ty = 0.0f;
#pragma unroll
        for (int w = 0; w < 8; ++w) {
            tx += red[w * 128 + lane];
            ty += red[w * 128 + lane + 64];
        }
        pooled[(size_t)g * 128 + lane]      = tx * (1.0f / 128.0f);
        pooled[(size_t)g * 128 + lane + 64] = ty * (1.0f / 128.0f);
    }
}

// ---------------- fused MLPs: 4 graph-rows per block ----------------
#define RB 4
__global__ __launch_bounds__(256) void k_mlp(const float* __restrict__ pooled,
                                             const float* __restrict__ w1a, const float* __restrict__ b1a,
                                             const float* __restrict__ w1b, const float* __restrict__ b1b,
                                             const float* __restrict__ w2a, const float* __restrict__ b2a,
                                             const float* __restrict__ w2b, const float* __restrict__ b2b,
                                             float* __restrict__ out, int B) {
    __shared__ float row[RB][128];
    __shared__ float hid[2][RB][256];
    int tid = threadIdx.x;
    int g0 = blockIdx.x * RB;

    for (int i = tid; i < RB * 128; i += 256)
        row[i >> 7][i & 127] = pooled[(size_t)g0 * 128 + i];
    __syncthreads();

    float a1[RB], a2[RB];
#pragma unroll
    for (int r = 0; r < RB; ++r) { a1[r] = 0.0f; a2[r] = 0.0f; }
    for (int k = 0; k < 128; ++k) {
        float wv1 = w1a[k * 256 + tid];
        float wv2 = w2a[k * 256 + tid];
#pragma unroll
        for (int r = 0; r < RB; ++r) {
            float xv = row[r][k];
            a1[r] += xv * wv1;
            a2[r] += xv * wv2;
        }
    }
    float bb1 = b1a[tid], bb2 = b2a[tid];
#pragma unroll
    for (int r = 0; r < RB; ++r) {
        hid[0][r][tid] = lrelu(a1[r] + bb1);
        hid[1][r][tid] = lrelu(a2[r] + bb2);
    }
    __syncthreads();

    int p = tid >> 7;
    int i = tid & 127;
    const float* wb = p ? w2b : w1b;
    const float* bvp = p ? b2b : b1b;
    float o[RB];
#pragma unroll
    for (int r = 0; r < RB; ++r) o[r] = 0.0f;
    for (int k = 0; k < 256; ++k) {
        float wv = wb[k * 128 + i];
#pragma unroll
        for (int r = 0; r < RB; ++r) o[r] += hid[p][r][k] * wv;
    }
    float bias = bvp[i];
#pragma unroll
    for (int r = 0; r < RB; ++r)
        out[(size_t)p * B * 128 + (size_t)(g0 + r) * 128 + i] = o[r] + bias;
}

extern "C" void kernel_launch(void* const* d_in, const int* in_sizes, int n_in,
                              void* d_out, int out_size, void* d_ws, size_t ws_size,
                              hipStream_t stream) {
    const float* x    = (const float*)d_in[0];
    const int*   edge = (const int*)d_in[1];
    const float* W    = (const float*)d_in[2];
    const float* b    = (const float*)d_in[3];
    const float* w1a  = (const float*)d_in[4];
    const float* b1a  = (const float*)d_in[5];
    const float* w1b  = (const float*)d_in[6];
    const float* b1b  = (const float*)d_in[7];
    const float* w2a  = (const float*)d_in[8];
    const float* b2a  = (const float*)d_in[9];
    const float* w2b  = (const float*)d_in[10];
    const float* b2b  = (const float*)d_in[11];

    int n = in_sizes[0] / 128;      // 131072 nodes
    int E = in_sizes[1] / 2;        // 2097152 edges
    int B = n / 128;                // 1024 graphs

    char* ws = (char*)d_ws;
    size_t off = 0;
    auto alloc = [&](size_t bytes) -> void* {
        void* p = ws + off;
        off = (off + bytes + 255) & ~(size_t)255;
        return p;
    };
    unsigned* h2      = (unsigned*)alloc((size_t)n * 64 * 4);      // bf16x2 rows, word c = (c, c+64)
    int*      buckets = (int*)alloc((size_t)B * BCAP * 4);         // 12.6 MB
    int*      bcnt    = (int*)alloc((size_t)B * 4);
    float*    dinv    = (float*)alloc((size_t)n * 4);
    float*    pooled  = (float*)alloc((size_t)B * 128 * 4);
    (void)ws_size; (void)n_in; (void)out_size;

    int eblk8 = (E + 256 * EPT - 1) / (256 * EPT);  // 1024

    hipMemsetAsync(bcnt, 0, (size_t)B * 4, stream);
    hipLaunchKernelGGL(k_bucket, dim3(eblk8), dim3(256), 0, stream, edge, E, bcnt, buckets);
    hipLaunchKernelGGL(k_deg,    dim3(B), dim3(256), 0, stream, buckets, bcnt, dinv);
    hipLaunchKernelGGL(k_gemm,   dim3(n / BM), dim3(256), 0, stream, x, W, h2);
    hipLaunchKernelGGL(k_aggr,   dim3(B), dim3(512), AGG_LDS, stream, h2, buckets, bcnt, dinv, b, pooled);
    hipLaunchKernelGGL(k_mlp,    dim3(B / RB), dim3(256), 0, stream,
                       pooled, w1a, b1a, w1b, b1b, w2a, b2a, w2b, b2b, (float*)d_out, B);
}

// Round 6
// 588.234 us; speedup vs baseline: 3.2248x; 3.2248x over previous
//
#include <hip/hip_runtime.h>

#define NEG_SLOPE 0.01f
#define EPT 8       // edges per thread in bucket kernel
#define BCAP 3072   // bucket capacity (mean 2048, sigma ~45 -> 22 sigma margin)

static __device__ __forceinline__ float lrelu(float v) {
    return v >= 0.0f ? v : NEG_SLOPE * v;
}

// bf16 pack/unpack (RNE)
static __device__ __forceinline__ unsigned pack_bf16(float a, float b) {
    unsigned ua = __float_as_uint(a);
    unsigned ub = __float_as_uint(b);
    ua = (ua + 0x7FFFu + ((ua >> 16) & 1u)) >> 16;
    ub = (ub + 0x7FFFu + ((ub >> 16) & 1u)) >> 16;
    return ua | (ub << 16);
}
static __device__ __forceinline__ float bflo(unsigned u) { return __uint_as_float(u << 16); }
static __device__ __forceinline__ float bfhi(unsigned u) { return __uint_as_float(u & 0xFFFF0000u); }

// ---------------- bucket edges by destination graph ----------------
// entry = (src << 7) | (dst & 127); bucket = dst >> 7.
__global__ void k_bucket(const int* __restrict__ edge, int E, int* bcnt, int* buckets) {
    int t = blockIdx.x * blockDim.x + threadIdx.x;
    int base = t * EPT;
    if (base + EPT <= E) {
        int4 sa = *(const int4*)&edge[base];
        int4 sb = *(const int4*)&edge[base + 4];
        int4 da = *(const int4*)&edge[E + base];
        int4 db = *(const int4*)&edge[E + base + 4];
        int g0 = da.x >> 7, g1 = da.y >> 7, g2 = da.z >> 7, g3 = da.w >> 7;
        int g4 = db.x >> 7, g5 = db.y >> 7, g6 = db.z >> 7, g7 = db.w >> 7;
        int e0 = (sa.x << 7) | (da.x & 127);
        int e1 = (sa.y << 7) | (da.y & 127);
        int e2 = (sa.z << 7) | (da.z & 127);
        int e3 = (sa.w << 7) | (da.w & 127);
        int e4 = (sb.x << 7) | (db.x & 127);
        int e5 = (sb.y << 7) | (db.y & 127);
        int e6 = (sb.z << 7) | (db.z & 127);
        int e7 = (sb.w << 7) | (db.w & 127);
        int p0 = atomicAdd(&bcnt[g0], 1);
        int p1 = atomicAdd(&bcnt[g1], 1);
        int p2 = atomicAdd(&bcnt[g2], 1);
        int p3 = atomicAdd(&bcnt[g3], 1);
        int p4 = atomicAdd(&bcnt[g4], 1);
        int p5 = atomicAdd(&bcnt[g5], 1);
        int p6 = atomicAdd(&bcnt[g6], 1);
        int p7 = atomicAdd(&bcnt[g7], 1);
        if (p0 < BCAP) buckets[g0 * BCAP + p0] = e0;
        if (p1 < BCAP) buckets[g1 * BCAP + p1] = e1;
        if (p2 < BCAP) buckets[g2 * BCAP + p2] = e2;
        if (p3 < BCAP) buckets[g3 * BCAP + p3] = e3;
        if (p4 < BCAP) buckets[g4 * BCAP + p4] = e4;
        if (p5 < BCAP) buckets[g5 * BCAP + p5] = e5;
        if (p6 < BCAP) buckets[g6 * BCAP + p6] = e6;
        if (p7 < BCAP) buckets[g7 * BCAP + p7] = e7;
    } else {
        for (int i = base; i < E; ++i) {
            int s = edge[i], d = edge[E + i];
            int g = d >> 7;
            int p = atomicAdd(&bcnt[g], 1);
            if (p < BCAP) buckets[g * BCAP + p] = (s << 7) | (d & 127);
        }
    }
}

// ---------------- per-graph degree histogram -> global dinv ----------------
__global__ __launch_bounds__(256) void k_deg(const int* __restrict__ buckets,
                                             const int* __restrict__ bcnt,
                                             float* __restrict__ dinv) {
    __shared__ int c[128];
    int g = blockIdx.x, tid = threadIdx.x;
    if (tid < 128) c[tid] = 0;
    __syncthreads();
    int m = min(bcnt[g], BCAP);
    const int* bk = &buckets[g * BCAP];
    for (int i = tid; i < m; i += 256) atomicAdd(&c[bk[i] & 127], 1);
    __syncthreads();
    if (tid < 128) dinv[g * 128 + tid] = rsqrtf((float)(c[tid] + 1));  // +1 self loop
}

// ---------------- h = x @ W  (fp32 compute, bf16 out; word c = feats (c, c+64)) ----
#define BM 64
#define BK 32
__global__ __launch_bounds__(256) void k_gemm(const float* __restrict__ x,
                                              const float* __restrict__ W,
                                              unsigned* __restrict__ h2) {
    __shared__ float Xs[BM][BK + 4];
    __shared__ float Ws[BK][128];
    int tid = threadIdx.x;
    int tx = tid & 15;
    int ty = tid >> 4;
    long r0 = (long)blockIdx.x * BM;

    float acc[4][8];
#pragma unroll
    for (int j = 0; j < 4; ++j)
#pragma unroll
        for (int c = 0; c < 8; ++c) acc[j][c] = 0.0f;

    for (int k0 = 0; k0 < 128; k0 += BK) {
#pragma unroll
        for (int it = 0; it < 2; ++it) {
            int i = tid + it * 256;
            int row = i >> 3;
            int kq = i & 7;
            float4 v = *(const float4*)&x[(r0 + row) * 128 + k0 + kq * 4];
            *(float4*)&Xs[row][kq * 4] = v;
        }
#pragma unroll
        for (int it = 0; it < 4; ++it) {
            int i = tid + it * 256;
            int kk = i >> 5;
            int cq = i & 31;
            *(float4*)&Ws[kk][cq * 4] = *(const float4*)&W[(k0 + kk) * 128 + cq * 4];
        }
        __syncthreads();

#pragma unroll
        for (int k = 0; k < BK; k += 4) {
            float4 xf[4];
#pragma unroll
            for (int j = 0; j < 4; ++j) xf[j] = *(const float4*)&Xs[ty * 4 + j][k];
#pragma unroll
            for (int kk = 0; kk < 4; ++kk) {
                float4 wa = *(const float4*)&Ws[k + kk][tx * 4];
                float4 wb = *(const float4*)&Ws[k + kk][tx * 4 + 64];
#pragma unroll
                for (int j = 0; j < 4; ++j) {
                    float xs = ((const float*)&xf[j])[kk];
                    acc[j][0] += xs * wa.x;
                    acc[j][1] += xs * wa.y;
                    acc[j][2] += xs * wa.z;
                    acc[j][3] += xs * wa.w;
                    acc[j][4] += xs * wb.x;
                    acc[j][5] += xs * wb.y;
                    acc[j][6] += xs * wb.z;
                    acc[j][7] += xs * wb.w;
                }
            }
        }
        __syncthreads();
    }
#pragma unroll
    for (int j = 0; j < 4; ++j) {
        long r = r0 + ty * 4 + j;
        uint4 pw;
        pw.x = pack_bf16(acc[j][0], acc[j][4]);
        pw.y = pack_bf16(acc[j][1], acc[j][5]);
        pw.z = pack_bf16(acc[j][2], acc[j][6]);
        pw.w = pack_bf16(acc[j][3], acc[j][7]);
        *(uint4*)&h2[r * 64 + tx * 4] = pw;
    }
}

// ---------------- aggregation: one block per graph ----------------
// Phase 1: counting-sort bucket by dst-local into LDS (int atomics only).
// Phase 2: one wave per node (16 nodes/wave), register accumulation,
//          shfl-broadcast + 4-deep independent h2 row gathers. No fp atomics.
__global__ __launch_bounds__(512) void k_aggr(const unsigned* __restrict__ h2,
                                              const int* __restrict__ buckets,
                                              const int* __restrict__ bcnt,
                                              const float* __restrict__ dinv,
                                              const float* __restrict__ bias,
                                              float* __restrict__ pooled) {
    __shared__ int cnt[128];
    __shared__ int incl[128];     // inclusive scan of cnt
    __shared__ int head[128];     // scatter cursors
    __shared__ int sorted[BCAP];  // bucket sorted by dst-local
    __shared__ float red[8][128];
    int tid = threadIdx.x;
    int wave = tid >> 6;
    int lane = tid & 63;
    int g = blockIdx.x;
    int m = min(bcnt[g], BCAP);
    const int* gbk = &buckets[g * BCAP];

    // histogram over dst-local
    if (tid < 128) cnt[tid] = 0;
    __syncthreads();
    for (int i = tid; i < m; i += 512) atomicAdd(&cnt[gbk[i] & 127], 1);
    __syncthreads();
    // inclusive scan (Hillis-Steele over 128 bins)
    if (tid < 128) incl[tid] = cnt[tid];
    __syncthreads();
    for (int off = 1; off < 128; off <<= 1) {
        int t = (tid < 128 && tid >= off) ? incl[tid - off] : 0;
        __syncthreads();
        if (tid < 128) incl[tid] += t;
        __syncthreads();
    }
    if (tid < 128) head[tid] = incl[tid] - cnt[tid];  // exclusive start
    __syncthreads();
    // scatter into sorted order (LDS int atomics, native)
    for (int i = tid; i < m; i += 512) {
        int e = gbk[i];
        int p = atomicAdd(&head[e & 127], 1);
        sorted[p] = e;
    }
    __syncthreads();

    float bx = bias[lane], by = bias[lane + 64];
    float accx = 0.0f, accy = 0.0f;

#pragma unroll 1
    for (int t = 0; t < 16; ++t) {
        int d = wave * 16 + t;
        int re = incl[d];
        int rs = re - cnt[d];
        int v = g * 128 + d;
        float dv = dinv[v];
        unsigned self = h2[(size_t)v * 64 + lane];
        float ex = 0.0f, ey = 0.0f;   // sum of h[src]*dinv[src]

        for (int base = rs; base < re; base += 64) {
            int mb = min(64, re - base);
            int entry = 0;
            float we = 0.0f;
            if (lane < mb) {
                entry = sorted[base + lane];
                we = dinv[entry >> 7];
            }
            int full = mb & ~3;
            for (int j = 0; j < full; j += 4) {
                int s0 = __shfl(entry, j);
                int s1 = __shfl(entry, j + 1);
                int s2 = __shfl(entry, j + 2);
                int s3 = __shfl(entry, j + 3);
                float w0 = __shfl(we, j);
                float w1 = __shfl(we, j + 1);
                float w2 = __shfl(we, j + 2);
                float w3 = __shfl(we, j + 3);
                unsigned u0 = h2[(size_t)(s0 >> 7) * 64 + lane];
                unsigned u1 = h2[(size_t)(s1 >> 7) * 64 + lane];
                unsigned u2 = h2[(size_t)(s2 >> 7) * 64 + lane];
                unsigned u3 = h2[(size_t)(s3 >> 7) * 64 + lane];
                ex += bflo(u0) * w0; ey += bfhi(u0) * w0;
                ex += bflo(u1) * w1; ey += bfhi(u1) * w1;
                ex += bflo(u2) * w2; ey += bfhi(u2) * w2;
                ex += bflo(u3) * w3; ey += bfhi(u3) * w3;
            }
            for (int j = full; j < mb; ++j) {
                int s0 = __shfl(entry, j);
                float w0 = __shfl(we, j);
                unsigned u0 = h2[(size_t)(s0 >> 7) * 64 + lane];
                ex += bflo(u0) * w0; ey += bfhi(u0) * w0;
            }
        }
        float dv2 = dv * dv;
        accx += lrelu(ex * dv + bflo(self) * dv2 + bx);
        accy += lrelu(ey * dv + bfhi(self) * dv2 + by);
    }

    red[wave][lane]      = accx;
    red[wave][lane + 64] = accy;
    __syncthreads();
    if (wave == 0) {
        float tx = 0.0f, ty = 0.0f;
#pragma unroll
        for (int w = 0; w < 8; ++w) {
            tx += red[w][lane];
            ty += red[w][lane + 64];
        }
        pooled[(size_t)g * 128 + lane]      = tx * (1.0f / 128.0f);
        pooled[(size_t)g * 128 + lane + 64] = ty * (1.0f / 128.0f);
    }
}

// ---------------- fused MLPs: 4 graph-rows per block ----------------
#define RB 4
__global__ __launch_bounds__(256) void k_mlp(const float* __restrict__ pooled,
                                             const float* __restrict__ w1a, const float* __restrict__ b1a,
                                             const float* __restrict__ w1b, const float* __restrict__ b1b,
                                             const float* __restrict__ w2a, const float* __restrict__ b2a,
                                             const float* __restrict__ w2b, const float* __restrict__ b2b,
                                             float* __restrict__ out, int B) {
    __shared__ float row[RB][128];
    __shared__ float hid[2][RB][256];
    int tid = threadIdx.x;
    int g0 = blockIdx.x * RB;

    for (int i = tid; i < RB * 128; i += 256)
        row[i >> 7][i & 127] = pooled[(size_t)g0 * 128 + i];
    __syncthreads();

    float a1[RB], a2[RB];
#pragma unroll
    for (int r = 0; r < RB; ++r) { a1[r] = 0.0f; a2[r] = 0.0f; }
    for (int k = 0; k < 128; ++k) {
        float wv1 = w1a[k * 256 + tid];
        float wv2 = w2a[k * 256 + tid];
#pragma unroll
        for (int r = 0; r < RB; ++r) {
            float xv = row[r][k];
            a1[r] += xv * wv1;
            a2[r] += xv * wv2;
        }
    }
    float bb1 = b1a[tid], bb2 = b2a[tid];
#pragma unroll
    for (int r = 0; r < RB; ++r) {
        hid[0][r][tid] = lrelu(a1[r] + bb1);
        hid[1][r][tid] = lrelu(a2[r] + bb2);
    }
    __syncthreads();

    int p = tid >> 7;
    int i = tid & 127;
    const float* wb = p ? w2b : w1b;
    const float* bvp = p ? b2b : b1b;
    float o[RB];
#pragma unroll
    for (int r = 0; r < RB; ++r) o[r] = 0.0f;
    for (int k = 0; k < 256; ++k) {
        float wv = wb[k * 128 + i];
#pragma unroll
        for (int r = 0; r < RB; ++r) o[r] += hid[p][r][k] * wv;
    }
    float bias = bvp[i];
#pragma unroll
    for (int r = 0; r < RB; ++r)
        out[(size_t)p * B * 128 + (size_t)(g0 + r) * 128 + i] = o[r] + bias;
}

extern "C" void kernel_launch(void* const* d_in, const int* in_sizes, int n_in,
                              void* d_out, int out_size, void* d_ws, size_t ws_size,
                              hipStream_t stream) {
    const float* x    = (const float*)d_in[0];
    const int*   edge = (const int*)d_in[1];
    const float* W    = (const float*)d_in[2];
    const float* b    = (const float*)d_in[3];
    const float* w1a  = (const float*)d_in[4];
    const float* b1a  = (const float*)d_in[5];
    const float* w1b  = (const float*)d_in[6];
    const float* b1b  = (const float*)d_in[7];
    const float* w2a  = (const float*)d_in[8];
    const float* b2a  = (const float*)d_in[9];
    const float* w2b  = (const float*)d_in[10];
    const float* b2b  = (const float*)d_in[11];

    int n = in_sizes[0] / 128;      // 131072 nodes
    int E = in_sizes[1] / 2;        // 2097152 edges
    int B = n / 128;                // 1024 graphs

    char* ws = (char*)d_ws;
    size_t off = 0;
    auto alloc = [&](size_t bytes) -> void* {
        void* p = ws + off;
        off = (off + bytes + 255) & ~(size_t)255;
        return p;
    };
    unsigned* h2      = (unsigned*)alloc((size_t)n * 64 * 4);      // bf16x2 rows, word c = (c, c+64)
    int*      buckets = (int*)alloc((size_t)B * BCAP * 4);         // 12.6 MB
    int*      bcnt    = (int*)alloc((size_t)B * 4);
    float*    dinv    = (float*)alloc((size_t)n * 4);
    float*    pooled  = (float*)alloc((size_t)B * 128 * 4);
    (void)ws_size; (void)n_in; (void)out_size;

    int eblk8 = (E + 256 * EPT - 1) / (256 * EPT);  // 1024

    hipMemsetAsync(bcnt, 0, (size_t)B * 4, stream);
    hipLaunchKernelGGL(k_bucket, dim3(eblk8), dim3(256), 0, stream, edge, E, bcnt, buckets);
    hipLaunchKernelGGL(k_deg,    dim3(B), dim3(256), 0, stream, buckets, bcnt, dinv);
    hipLaunchKernelGGL(k_gemm,   dim3(n / BM), dim3(256), 0, stream, x, W, h2);
    hipLaunchKernelGGL(k_aggr,   dim3(B), dim3(512), 0, stream, h2, buckets, bcnt, dinv, b, pooled);
    hipLaunchKernelGGL(k_mlp,    dim3(B / RB), dim3(256), 0, stream,
                       pooled, w1a, b1a, w1b, b1b, w2a, b2a, w2b, b2b, (float*)d_out, B);
}

// Round 7
// 258.515 us; speedup vs baseline: 7.3379x; 2.2754x over previous
//
#include <hip/hip_runtime.h>

#define NEG_SLOPE 0.01f
#define EPT 8        // edges per thread in bucket kernel
#define NREP 8       // bucket replicas (~per-XCD via blockIdx&7)
#define SUBCAP 448   // per-(graph,replica) capacity: mean 256, sigma 16 -> +12 sigma
#define CSTRIDE 16   // counter padding: 16 ints = 64B line per counter
#define SCAP (NREP * SUBCAP)  // 3584 LDS sort capacity per graph

static __device__ __forceinline__ float lrelu(float v) {
    return v >= 0.0f ? v : NEG_SLOPE * v;
}

// bf16 pack/unpack (RNE)
static __device__ __forceinline__ unsigned pack_bf16(float a, float b) {
    unsigned ua = __float_as_uint(a);
    unsigned ub = __float_as_uint(b);
    ua = (ua + 0x7FFFu + ((ua >> 16) & 1u)) >> 16;
    ub = (ub + 0x7FFFu + ((ub >> 16) & 1u)) >> 16;
    return ua | (ub << 16);
}
static __device__ __forceinline__ float bflo(unsigned u) { return __uint_as_float(u << 16); }
static __device__ __forceinline__ float bfhi(unsigned u) { return __uint_as_float(u & 0xFFFF0000u); }

// ---------------- bucket edges by destination graph (replicated, padded) ----------
// entry = (src << 7) | (dst & 127); bucket = dst >> 7; replica = blockIdx & 7.
__global__ void k_bucket(const int* __restrict__ edge, int E, int B,
                         int* __restrict__ bcnt, int* __restrict__ buckets) {
    int rep = blockIdx.x & (NREP - 1);
    int* mycnt = bcnt + (size_t)rep * B * CSTRIDE;
    int* mybk  = buckets + (size_t)rep * B * SUBCAP;
    int t = blockIdx.x * blockDim.x + threadIdx.x;
    int base = t * EPT;
    if (base + EPT <= E) {
        int4 sa = *(const int4*)&edge[base];
        int4 sb = *(const int4*)&edge[base + 4];
        int4 da = *(const int4*)&edge[E + base];
        int4 db = *(const int4*)&edge[E + base + 4];
        int g0 = da.x >> 7, g1 = da.y >> 7, g2 = da.z >> 7, g3 = da.w >> 7;
        int g4 = db.x >> 7, g5 = db.y >> 7, g6 = db.z >> 7, g7 = db.w >> 7;
        int e0 = (sa.x << 7) | (da.x & 127);
        int e1 = (sa.y << 7) | (da.y & 127);
        int e2 = (sa.z << 7) | (da.z & 127);
        int e3 = (sa.w << 7) | (da.w & 127);
        int e4 = (sb.x << 7) | (db.x & 127);
        int e5 = (sb.y << 7) | (db.y & 127);
        int e6 = (sb.z << 7) | (db.z & 127);
        int e7 = (sb.w << 7) | (db.w & 127);
        int p0 = atomicAdd(&mycnt[g0 * CSTRIDE], 1);
        int p1 = atomicAdd(&mycnt[g1 * CSTRIDE], 1);
        int p2 = atomicAdd(&mycnt[g2 * CSTRIDE], 1);
        int p3 = atomicAdd(&mycnt[g3 * CSTRIDE], 1);
        int p4 = atomicAdd(&mycnt[g4 * CSTRIDE], 1);
        int p5 = atomicAdd(&mycnt[g5 * CSTRIDE], 1);
        int p6 = atomicAdd(&mycnt[g6 * CSTRIDE], 1);
        int p7 = atomicAdd(&mycnt[g7 * CSTRIDE], 1);
        if (p0 < SUBCAP) mybk[g0 * SUBCAP + p0] = e0;
        if (p1 < SUBCAP) mybk[g1 * SUBCAP + p1] = e1;
        if (p2 < SUBCAP) mybk[g2 * SUBCAP + p2] = e2;
        if (p3 < SUBCAP) mybk[g3 * SUBCAP + p3] = e3;
        if (p4 < SUBCAP) mybk[g4 * SUBCAP + p4] = e4;
        if (p5 < SUBCAP) mybk[g5 * SUBCAP + p5] = e5;
        if (p6 < SUBCAP) mybk[g6 * SUBCAP + p6] = e6;
        if (p7 < SUBCAP) mybk[g7 * SUBCAP + p7] = e7;
    } else {
        for (int i = base; i < E; ++i) {
            int s = edge[i], d = edge[E + i];
            int g = d >> 7;
            int p = atomicAdd(&mycnt[g * CSTRIDE], 1);
            if (p < SUBCAP) mybk[g * SUBCAP + p] = (s << 7) | (d & 127);
        }
    }
}

// ---------------- per-graph degree histogram -> global dinv ----------------
__global__ __launch_bounds__(256) void k_deg(const int* __restrict__ buckets,
                                             const int* __restrict__ bcnt,
                                             float* __restrict__ dinv, int B) {
    __shared__ int c[128];
    int g = blockIdx.x, tid = threadIdx.x;
    if (tid < 128) c[tid] = 0;
    __syncthreads();
    for (int r = 0; r < NREP; ++r) {
        int m = min(bcnt[(size_t)r * B * CSTRIDE + g * CSTRIDE], SUBCAP);
        const int* bk = &buckets[((size_t)r * B + g) * SUBCAP];
        for (int i = tid; i < m; i += 256) atomicAdd(&c[bk[i] & 127], 1);
    }
    __syncthreads();
    if (tid < 128) dinv[g * 128 + tid] = rsqrtf((float)(c[tid] + 1));  // +1 self loop
}

// ---------------- h = x @ W  (fp32 compute, bf16 out; word c = feats (c, c+64)) ----
#define BM 64
#define BK 32
__global__ __launch_bounds__(256) void k_gemm(const float* __restrict__ x,
                                              const float* __restrict__ W,
                                              unsigned* __restrict__ h2) {
    __shared__ float Xs[BM][BK + 4];
    __shared__ float Ws[BK][128];
    int tid = threadIdx.x;
    int tx = tid & 15;
    int ty = tid >> 4;
    long r0 = (long)blockIdx.x * BM;

    float acc[4][8];
#pragma unroll
    for (int j = 0; j < 4; ++j)
#pragma unroll
        for (int c = 0; c < 8; ++c) acc[j][c] = 0.0f;

    for (int k0 = 0; k0 < 128; k0 += BK) {
#pragma unroll
        for (int it = 0; it < 2; ++it) {
            int i = tid + it * 256;
            int row = i >> 3;
            int kq = i & 7;
            float4 v = *(const float4*)&x[(r0 + row) * 128 + k0 + kq * 4];
            *(float4*)&Xs[row][kq * 4] = v;
        }
#pragma unroll
        for (int it = 0; it < 4; ++it) {
            int i = tid + it * 256;
            int kk = i >> 5;
            int cq = i & 31;
            *(float4*)&Ws[kk][cq * 4] = *(const float4*)&W[(k0 + kk) * 128 + cq * 4];
        }
        __syncthreads();

#pragma unroll
        for (int k = 0; k < BK; k += 4) {
            float4 xf[4];
#pragma unroll
            for (int j = 0; j < 4; ++j) xf[j] = *(const float4*)&Xs[ty * 4 + j][k];
#pragma unroll
            for (int kk = 0; kk < 4; ++kk) {
                float4 wa = *(const float4*)&Ws[k + kk][tx * 4];
                float4 wb = *(const float4*)&Ws[k + kk][tx * 4 + 64];
#pragma unroll
                for (int j = 0; j < 4; ++j) {
                    float xs = ((const float*)&xf[j])[kk];
                    acc[j][0] += xs * wa.x;
                    acc[j][1] += xs * wa.y;
                    acc[j][2] += xs * wa.z;
                    acc[j][3] += xs * wa.w;
                    acc[j][4] += xs * wb.x;
                    acc[j][5] += xs * wb.y;
                    acc[j][6] += xs * wb.z;
                    acc[j][7] += xs * wb.w;
                }
            }
        }
        __syncthreads();
    }
#pragma unroll
    for (int j = 0; j < 4; ++j) {
        long r = r0 + ty * 4 + j;
        uint4 pw;
        pw.x = pack_bf16(acc[j][0], acc[j][4]);
        pw.y = pack_bf16(acc[j][1], acc[j][5]);
        pw.z = pack_bf16(acc[j][2], acc[j][6]);
        pw.w = pack_bf16(acc[j][3], acc[j][7]);
        *(uint4*)&h2[r * 64 + tx * 4] = pw;
    }
}

// ---------------- aggregation: one block per graph ----------------
// Phase 1: counting-sort the 8 sub-buckets by dst-local into LDS (int atomics).
// Phase 2: one wave per node (16 nodes/wave), register accumulation,
//          shfl-broadcast + 4-deep independent h2 row gathers. No fp atomics.
__global__ __launch_bounds__(512) void k_aggr(const unsigned* __restrict__ h2,
                                              const int* __restrict__ buckets,
                                              const int* __restrict__ bcnt,
                                              const float* __restrict__ dinv,
                                              const float* __restrict__ bias,
                                              float* __restrict__ pooled, int B) {
    __shared__ int cnt[128];
    __shared__ int incl[128];     // inclusive scan of cnt
    __shared__ int head[128];     // scatter cursors
    __shared__ int sorted[SCAP];  // edges sorted by dst-local
    __shared__ float red[8][128];
    int tid = threadIdx.x;
    int wave = tid >> 6;
    int lane = tid & 63;
    int g = blockIdx.x;

    // histogram over dst-local
    if (tid < 128) cnt[tid] = 0;
    __syncthreads();
    for (int r = 0; r < NREP; ++r) {
        int m = min(bcnt[(size_t)r * B * CSTRIDE + g * CSTRIDE], SUBCAP);
        const int* bk = &buckets[((size_t)r * B + g) * SUBCAP];
        for (int i = tid; i < m; i += 512) atomicAdd(&cnt[bk[i] & 127], 1);
    }
    __syncthreads();
    // inclusive scan (Hillis-Steele over 128 bins)
    if (tid < 128) incl[tid] = cnt[tid];
    __syncthreads();
    for (int off = 1; off < 128; off <<= 1) {
        int t = (tid < 128 && tid >= off) ? incl[tid - off] : 0;
        __syncthreads();
        if (tid < 128) incl[tid] += t;
        __syncthreads();
    }
    if (tid < 128) head[tid] = incl[tid] - cnt[tid];  // exclusive start
    __syncthreads();
    // scatter into sorted order (LDS int atomics, native)
    for (int r = 0; r < NREP; ++r) {
        int m = min(bcnt[(size_t)r * B * CSTRIDE + g * CSTRIDE], SUBCAP);
        const int* bk = &buckets[((size_t)r * B + g) * SUBCAP];
        for (int i = tid; i < m; i += 512) {
            int e = bk[i];
            int p = atomicAdd(&head[e & 127], 1);
            sorted[p] = e;
        }
    }
    __syncthreads();

    float bx = bias[lane], by = bias[lane + 64];
    float accx = 0.0f, accy = 0.0f;

#pragma unroll 1
    for (int t = 0; t < 16; ++t) {
        int d = wave * 16 + t;
        int re = incl[d];
        int rs = re - cnt[d];
        int v = g * 128 + d;
        float dv = dinv[v];
        unsigned self = h2[(size_t)v * 64 + lane];
        float ex = 0.0f, ey = 0.0f;   // sum of h[src]*dinv[src]

        for (int base = rs; base < re; base += 64) {
            int mb = min(64, re - base);
            int entry = 0;
            float we = 0.0f;
            if (lane < mb) {
                entry = sorted[base + lane];
                we = dinv[entry >> 7];
            }
            int full = mb & ~3;
            for (int j = 0; j < full; j += 4) {
                int s0 = __shfl(entry, j);
                int s1 = __shfl(entry, j + 1);
                int s2 = __shfl(entry, j + 2);
                int s3 = __shfl(entry, j + 3);
                float w0 = __shfl(we, j);
                float w1 = __shfl(we, j + 1);
                float w2 = __shfl(we, j + 2);
                float w3 = __shfl(we, j + 3);
                unsigned u0 = h2[(size_t)(s0 >> 7) * 64 + lane];
                unsigned u1 = h2[(size_t)(s1 >> 7) * 64 + lane];
                unsigned u2 = h2[(size_t)(s2 >> 7) * 64 + lane];
                unsigned u3 = h2[(size_t)(s3 >> 7) * 64 + lane];
                ex += bflo(u0) * w0; ey += bfhi(u0) * w0;
                ex += bflo(u1) * w1; ey += bfhi(u1) * w1;
                ex += bflo(u2) * w2; ey += bfhi(u2) * w2;
                ex += bflo(u3) * w3; ey += bfhi(u3) * w3;
            }
            for (int j = full; j < mb; ++j) {
                int s0 = __shfl(entry, j);
                float w0 = __shfl(we, j);
                unsigned u0 = h2[(size_t)(s0 >> 7) * 64 + lane];
                ex += bflo(u0) * w0; ey += bfhi(u0) * w0;
            }
        }
        float dv2 = dv * dv;
        accx += lrelu(ex * dv + bflo(self) * dv2 + bx);
        accy += lrelu(ey * dv + bfhi(self) * dv2 + by);
    }

    red[wave][lane]      = accx;
    red[wave][lane + 64] = accy;
    __syncthreads();
    if (wave == 0) {
        float tx = 0.0f, ty = 0.0f;
#pragma unroll
        for (int w = 0; w < 8; ++w) {
            tx += red[w][lane];
            ty += red[w][lane + 64];
        }
        pooled[(size_t)g * 128 + lane]      = tx * (1.0f / 128.0f);
        pooled[(size_t)g * 128 + lane + 64] = ty * (1.0f / 128.0f);
    }
}

// ---------------- fused MLPs: 4 graph-rows per block ----------------
#define RB 4
__global__ __launch_bounds__(256) void k_mlp(const float* __restrict__ pooled,
                                             const float* __restrict__ w1a, const float* __restrict__ b1a,
                                             const float* __restrict__ w1b, const float* __restrict__ b1b,
                                             const float* __restrict__ w2a, const float* __restrict__ b2a,
                                             const float* __restrict__ w2b, const float* __restrict__ b2b,
                                             float* __restrict__ out, int B) {
    __shared__ float row[RB][128];
    __shared__ float hid[2][RB][256];
    int tid = threadIdx.x;
    int g0 = blockIdx.x * RB;

    for (int i = tid; i < RB * 128; i += 256)
        row[i >> 7][i & 127] = pooled[(size_t)g0 * 128 + i];
    __syncthreads();

    float a1[RB], a2[RB];
#pragma unroll
    for (int r = 0; r < RB; ++r) { a1[r] = 0.0f; a2[r] = 0.0f; }
    for (int k = 0; k < 128; ++k) {
        float wv1 = w1a[k * 256 + tid];
        float wv2 = w2a[k * 256 + tid];
#pragma unroll
        for (int r = 0; r < RB; ++r) {
            float xv = row[r][k];
            a1[r] += xv * wv1;
            a2[r] += xv * wv2;
        }
    }
    float bb1 = b1a[tid], bb2 = b2a[tid];
#pragma unroll
    for (int r = 0; r < RB; ++r) {
        hid[0][r][tid] = lrelu(a1[r] + bb1);
        hid[1][r][tid] = lrelu(a2[r] + bb2);
    }
    __syncthreads();

    int p = tid >> 7;
    int i = tid & 127;
    const float* wb = p ? w2b : w1b;
    const float* bvp = p ? b2b : b1b;
    float o[RB];
#pragma unroll
    for (int r = 0; r < RB; ++r) o[r] = 0.0f;
    for (int k = 0; k < 256; ++k) {
        float wv = wb[k * 128 + i];
#pragma unroll
        for (int r = 0; r < RB; ++r) o[r] += hid[p][r][k] * wv;
    }
    float bias = bvp[i];
#pragma unroll
    for (int r = 0; r < RB; ++r)
        out[(size_t)p * B * 128 + (size_t)(g0 + r) * 128 + i] = o[r] + bias;
}

extern "C" void kernel_launch(void* const* d_in, const int* in_sizes, int n_in,
                              void* d_out, int out_size, void* d_ws, size_t ws_size,
                              hipStream_t stream) {
    const float* x    = (const float*)d_in[0];
    const int*   edge = (const int*)d_in[1];
    const float* W    = (const float*)d_in[2];
    const float* b    = (const float*)d_in[3];
    const float* w1a  = (const float*)d_in[4];
    const float* b1a  = (const float*)d_in[5];
    const float* w1b  = (const float*)d_in[6];
    const float* b1b  = (const float*)d_in[7];
    const float* w2a  = (const float*)d_in[8];
    const float* b2a  = (const float*)d_in[9];
    const float* w2b  = (const float*)d_in[10];
    const float* b2b  = (const float*)d_in[11];

    int n = in_sizes[0] / 128;      // 131072 nodes
    int E = in_sizes[1] / 2;        // 2097152 edges
    int B = n / 128;                // 1024 graphs

    char* ws = (char*)d_ws;
    size_t off = 0;
    auto alloc = [&](size_t bytes) -> void* {
        void* p = ws + off;
        off = (off + bytes + 255) & ~(size_t)255;
        return p;
    };
    unsigned* h2      = (unsigned*)alloc((size_t)n * 64 * 4);                  // bf16x2 rows
    int*      buckets = (int*)alloc((size_t)NREP * B * SUBCAP * 4);            // 14.7 MB
    int*      bcnt    = (int*)alloc((size_t)NREP * B * CSTRIDE * 4);           // 512 KB padded counters
    float*    dinv    = (float*)alloc((size_t)n * 4);
    float*    pooled  = (float*)alloc((size_t)B * 128 * 4);
    (void)ws_size; (void)n_in; (void)out_size;

    int eblk8 = (E + 256 * EPT - 1) / (256 * EPT);  // 1024

    hipMemsetAsync(bcnt, 0, (size_t)NREP * B * CSTRIDE * 4, stream);
    hipLaunchKernelGGL(k_bucket, dim3(eblk8), dim3(256), 0, stream, edge, E, B, bcnt, buckets);
    hipLaunchKernelGGL(k_deg,    dim3(B), dim3(256), 0, stream, buckets, bcnt, dinv, B);
    hipLaunchKernelGGL(k_gemm,   dim3(n / BM), dim3(256), 0, stream, x, W, h2);
    hipLaunchKernelGGL(k_aggr,   dim3(B), dim3(512), 0, stream, h2, buckets, bcnt, dinv, b, pooled, B);
    hipLaunchKernelGGL(k_mlp,    dim3(B / RB), dim3(256), 0, stream,
                       pooled, w1a, b1a, w1b, b1b, w2a, b2a, w2b, b2b, (float*)d_out, B);
}

// Round 8
// 194.375 us; speedup vs baseline: 9.7592x; 1.3300x over previous
//
#include <hip/hip_runtime.h>

#define NEG_SLOPE 0.01f
#define BCAP 3072    // per-graph bucket capacity (mean 2048, sigma ~45)
#define CSTRIDE 16   // counter padding: 64B line per counter
#define BLKB 1024    // threads per bucket block
#define EPTB 16      // edges per thread in bucket kernel (16K edges/block)

static __device__ __forceinline__ float lrelu(float v) {
    return v >= 0.0f ? v : NEG_SLOPE * v;
}

// bf16 pack/unpack (RNE)
static __device__ __forceinline__ unsigned pack_bf16(float a, float b) {
    unsigned ua = __float_as_uint(a);
    unsigned ub = __float_as_uint(b);
    ua = (ua + 0x7FFFu + ((ua >> 16) & 1u)) >> 16;
    ub = (ub + 0x7FFFu + ((ub >> 16) & 1u)) >> 16;
    return ua | (ub << 16);
}
static __device__ __forceinline__ float bflo(unsigned u) { return __uint_as_float(u << 16); }
static __device__ __forceinline__ float bfhi(unsigned u) { return __uint_as_float(u & 0xFFFF0000u); }

// ---------------- bucket edges by dst graph: two-level LDS binning ----------------
// Per block: LDS histogram over graphs -> ONE global atomicAdd per (block,graph)
// -> contiguous run writes (full lines, no per-edge global atomics).
__global__ __launch_bounds__(BLKB) void k_bucket(const int* __restrict__ edge, int E, int B,
                                                 int* __restrict__ bcnt, int* __restrict__ buckets) {
    __shared__ int hist[1024];
    __shared__ int rbase[1024];
    int tid = threadIdx.x;
    if (tid < B) hist[tid] = 0;
    __syncthreads();

    int start = blockIdx.x * (BLKB * EPTB) + tid * EPTB;
    int entry[EPTB];
    int gg[EPTB];
    int nloc = 0;

    if (start + EPTB <= E) {
#pragma unroll
        for (int q = 0; q < EPTB / 4; ++q) {
            int4 s4 = *(const int4*)&edge[start + q * 4];
            int4 d4 = *(const int4*)&edge[E + start + q * 4];
            entry[q * 4 + 0] = (s4.x << 7) | (d4.x & 127); gg[q * 4 + 0] = d4.x >> 7;
            entry[q * 4 + 1] = (s4.y << 7) | (d4.y & 127); gg[q * 4 + 1] = d4.y >> 7;
            entry[q * 4 + 2] = (s4.z << 7) | (d4.z & 127); gg[q * 4 + 2] = d4.z >> 7;
            entry[q * 4 + 3] = (s4.w << 7) | (d4.w & 127); gg[q * 4 + 3] = d4.w >> 7;
        }
        nloc = EPTB;
    } else {
#pragma unroll
        for (int i = 0; i < EPTB; ++i) {
            if (start + i < E) {
                int s = edge[start + i], d = edge[E + start + i];
                entry[i] = (s << 7) | (d & 127);
                gg[i] = d >> 7;
                nloc = i + 1;
            }
        }
    }
#pragma unroll
    for (int i = 0; i < EPTB; ++i)
        if (i < nloc) atomicAdd(&hist[gg[i]], 1);
    __syncthreads();

    if (tid < B) {
        int c = hist[tid];
        rbase[tid] = (c > 0) ? atomicAdd(&bcnt[tid * CSTRIDE], c) : 0;
        hist[tid] = 0;   // reuse as run cursor
    }
    __syncthreads();

#pragma unroll
    for (int i = 0; i < EPTB; ++i) {
        if (i < nloc) {
            int g = gg[i];
            int pos = rbase[g] + atomicAdd(&hist[g], 1);
            if (pos < BCAP) buckets[(size_t)g * BCAP + pos] = entry[i];
        }
    }
}

// ---------------- per-graph degree histogram -> global dinv ----------------
__global__ __launch_bounds__(256) void k_deg(const int* __restrict__ buckets,
                                             const int* __restrict__ bcnt,
                                             float* __restrict__ dinv) {
    __shared__ int c[128];
    int g = blockIdx.x, tid = threadIdx.x;
    if (tid < 128) c[tid] = 0;
    __syncthreads();
    int m = min(bcnt[g * CSTRIDE], BCAP);
    const int* bk = &buckets[(size_t)g * BCAP];
    for (int i = tid; i < m; i += 256) atomicAdd(&c[bk[i] & 127], 1);
    __syncthreads();
    if (tid < 128) dinv[g * 128 + tid] = rsqrtf((float)(c[tid] + 1));  // +1 self loop
}

// ---------------- h = x @ W  (fp32 compute, bf16 out; word c = feats (c, c+64)) ----
#define BM 64
#define BK 32
__global__ __launch_bounds__(256) void k_gemm(const float* __restrict__ x,
                                              const float* __restrict__ W,
                                              unsigned* __restrict__ h2) {
    __shared__ float Xs[BM][BK + 4];
    __shared__ float Ws[BK][128];
    int tid = threadIdx.x;
    int tx = tid & 15;
    int ty = tid >> 4;
    long r0 = (long)blockIdx.x * BM;

    float acc[4][8];
#pragma unroll
    for (int j = 0; j < 4; ++j)
#pragma unroll
        for (int c = 0; c < 8; ++c) acc[j][c] = 0.0f;

    for (int k0 = 0; k0 < 128; k0 += BK) {
#pragma unroll
        for (int it = 0; it < 2; ++it) {
            int i = tid + it * 256;
            int row = i >> 3;
            int kq = i & 7;
            float4 v = *(const float4*)&x[(r0 + row) * 128 + k0 + kq * 4];
            *(float4*)&Xs[row][kq * 4] = v;
        }
#pragma unroll
        for (int it = 0; it < 4; ++it) {
            int i = tid + it * 256;
            int kk = i >> 5;
            int cq = i & 31;
            *(float4*)&Ws[kk][cq * 4] = *(const float4*)&W[(k0 + kk) * 128 + cq * 4];
        }
        __syncthreads();

#pragma unroll
        for (int k = 0; k < BK; k += 4) {
            float4 xf[4];
#pragma unroll
            for (int j = 0; j < 4; ++j) xf[j] = *(const float4*)&Xs[ty * 4 + j][k];
#pragma unroll
            for (int kk = 0; kk < 4; ++kk) {
                float4 wa = *(const float4*)&Ws[k + kk][tx * 4];
                float4 wb = *(const float4*)&Ws[k + kk][tx * 4 + 64];
#pragma unroll
                for (int j = 0; j < 4; ++j) {
                    float xs = ((const float*)&xf[j])[kk];
                    acc[j][0] += xs * wa.x;
                    acc[j][1] += xs * wa.y;
                    acc[j][2] += xs * wa.z;
                    acc[j][3] += xs * wa.w;
                    acc[j][4] += xs * wb.x;
                    acc[j][5] += xs * wb.y;
                    acc[j][6] += xs * wb.z;
                    acc[j][7] += xs * wb.w;
                }
            }
        }
        __syncthreads();
    }
#pragma unroll
    for (int j = 0; j < 4; ++j) {
        long r = r0 + ty * 4 + j;
        uint4 pw;
        pw.x = pack_bf16(acc[j][0], acc[j][4]);
        pw.y = pack_bf16(acc[j][1], acc[j][5]);
        pw.z = pack_bf16(acc[j][2], acc[j][6]);
        pw.w = pack_bf16(acc[j][3], acc[j][7]);
        *(uint4*)&h2[r * 64 + tx * 4] = pw;
    }
}

// ---------------- aggregation: one block per graph ----------------
// Phase 1: counting-sort bucket by dst-local into LDS (int atomics only).
// Phase 2: one wave per node (16 nodes/wave), register accumulation,
//          shfl-broadcast + 4-deep independent h2 row gathers. No fp atomics.
__global__ __launch_bounds__(512) void k_aggr(const unsigned* __restrict__ h2,
                                              const int* __restrict__ buckets,
                                              const int* __restrict__ bcnt,
                                              const float* __restrict__ dinv,
                                              const float* __restrict__ bias,
                                              float* __restrict__ pooled) {
    __shared__ int cnt[128];
    __shared__ int incl[128];
    __shared__ int head[128];
    __shared__ int sorted[BCAP];
    __shared__ float red[8][128];
    int tid = threadIdx.x;
    int wave = tid >> 6;
    int lane = tid & 63;
    int g = blockIdx.x;
    int m = min(bcnt[g * CSTRIDE], BCAP);
    const int* gbk = &buckets[(size_t)g * BCAP];

    if (tid < 128) cnt[tid] = 0;
    __syncthreads();
    for (int i = tid; i < m; i += 512) atomicAdd(&cnt[gbk[i] & 127], 1);
    __syncthreads();
    if (tid < 128) incl[tid] = cnt[tid];
    __syncthreads();
    for (int off = 1; off < 128; off <<= 1) {
        int t = (tid < 128 && tid >= off) ? incl[tid - off] : 0;
        __syncthreads();
        if (tid < 128) incl[tid] += t;
        __syncthreads();
    }
    if (tid < 128) head[tid] = incl[tid] - cnt[tid];
    __syncthreads();
    for (int i = tid; i < m; i += 512) {
        int e = gbk[i];
        int p = atomicAdd(&head[e & 127], 1);
        sorted[p] = e;
    }
    __syncthreads();

    float bx = bias[lane], by = bias[lane + 64];
    float accx = 0.0f, accy = 0.0f;

#pragma unroll 1
    for (int t = 0; t < 16; ++t) {
        int d = wave * 16 + t;
        int re = incl[d];
        int rs = re - cnt[d];
        int v = g * 128 + d;
        float dv = dinv[v];
        unsigned self = h2[(size_t)v * 64 + lane];
        float ex = 0.0f, ey = 0.0f;

        for (int base = rs; base < re; base += 64) {
            int mb = min(64, re - base);
            int entry = 0;
            float we = 0.0f;
            if (lane < mb) {
                entry = sorted[base + lane];
                we = dinv[entry >> 7];
            }
            int full = mb & ~3;
            for (int j = 0; j < full; j += 4) {
                int s0 = __shfl(entry, j);
                int s1 = __shfl(entry, j + 1);
                int s2 = __shfl(entry, j + 2);
                int s3 = __shfl(entry, j + 3);
                float w0 = __shfl(we, j);
                float w1 = __shfl(we, j + 1);
                float w2 = __shfl(we, j + 2);
                float w3 = __shfl(we, j + 3);
                unsigned u0 = h2[(size_t)(s0 >> 7) * 64 + lane];
                unsigned u1 = h2[(size_t)(s1 >> 7) * 64 + lane];
                unsigned u2 = h2[(size_t)(s2 >> 7) * 64 + lane];
                unsigned u3 = h2[(size_t)(s3 >> 7) * 64 + lane];
                ex += bflo(u0) * w0; ey += bfhi(u0) * w0;
                ex += bflo(u1) * w1; ey += bfhi(u1) * w1;
                ex += bflo(u2) * w2; ey += bfhi(u2) * w2;
                ex += bflo(u3) * w3; ey += bfhi(u3) * w3;
            }
            for (int j = full; j < mb; ++j) {
                int s0 = __shfl(entry, j);
                float w0 = __shfl(we, j);
                unsigned u0 = h2[(size_t)(s0 >> 7) * 64 + lane];
                ex += bflo(u0) * w0; ey += bfhi(u0) * w0;
            }
        }
        float dv2 = dv * dv;
        accx += lrelu(ex * dv + bflo(self) * dv2 + bx);
        accy += lrelu(ey * dv + bfhi(self) * dv2 + by);
    }

    red[wave][lane]      = accx;
    red[wave][lane + 64] = accy;
    __syncthreads();
    if (wave == 0) {
        float tx = 0.0f, ty = 0.0f;
#pragma unroll
        for (int w = 0; w < 8; ++w) {
            tx += red[w][lane];
            ty += red[w][lane + 64];
        }
        pooled[(size_t)g * 128 + lane]      = tx * (1.0f / 128.0f);
        pooled[(size_t)g * 128 + lane + 64] = ty * (1.0f / 128.0f);
    }
}

// ---------------- fused MLPs: 4 graph-rows per block ----------------
#define RB 4
__global__ __launch_bounds__(256) void k_mlp(const float* __restrict__ pooled,
                                             const float* __restrict__ w1a, const float* __restrict__ b1a,
                                             const float* __restrict__ w1b, const float* __restrict__ b1b,
                                             const float* __restrict__ w2a, const float* __restrict__ b2a,
                                             const float* __restrict__ w2b, const float* __restrict__ b2b,
                                             float* __restrict__ out, int B) {
    __shared__ float row[RB][128];
    __shared__ float hid[2][RB][256];
    int tid = threadIdx.x;
    int g0 = blockIdx.x * RB;

    for (int i = tid; i < RB * 128; i += 256)
        row[i >> 7][i & 127] = pooled[(size_t)g0 * 128 + i];
    __syncthreads();

    float a1[RB], a2[RB];
#pragma unroll
    for (int r = 0; r < RB; ++r) { a1[r] = 0.0f; a2[r] = 0.0f; }
    for (int k = 0; k < 128; ++k) {
        float wv1 = w1a[k * 256 + tid];
        float wv2 = w2a[k * 256 + tid];
#pragma unroll
        for (int r = 0; r < RB; ++r) {
            float xv = row[r][k];
            a1[r] += xv * wv1;
            a2[r] += xv * wv2;
        }
    }
    float bb1 = b1a[tid], bb2 = b2a[tid];
#pragma unroll
    for (int r = 0; r < RB; ++r) {
        hid[0][r][tid] = lrelu(a1[r] + bb1);
        hid[1][r][tid] = lrelu(a2[r] + bb2);
    }
    __syncthreads();

    int p = tid >> 7;
    int i = tid & 127;
    const float* wb = p ? w2b : w1b;
    const float* bvp = p ? b2b : b1b;
    float o[RB];
#pragma unroll
    for (int r = 0; r < RB; ++r) o[r] = 0.0f;
    for (int k = 0; k < 256; ++k) {
        float wv = wb[k * 128 + i];
#pragma unroll
        for (int r = 0; r < RB; ++r) o[r] += hid[p][r][k] * wv;
    }
    float bias = bvp[i];
#pragma unroll
    for (int r = 0; r < RB; ++r)
        out[(size_t)p * B * 128 + (size_t)(g0 + r) * 128 + i] = o[r] + bias;
}

extern "C" void kernel_launch(void* const* d_in, const int* in_sizes, int n_in,
                              void* d_out, int out_size, void* d_ws, size_t ws_size,
                              hipStream_t stream) {
    const float* x    = (const float*)d_in[0];
    const int*   edge = (const int*)d_in[1];
    const float* W    = (const float*)d_in[2];
    const float* b    = (const float*)d_in[3];
    const float* w1a  = (const float*)d_in[4];
    const float* b1a  = (const float*)d_in[5];
    const float* w1b  = (const float*)d_in[6];
    const float* b1b  = (const float*)d_in[7];
    const float* w2a  = (const float*)d_in[8];
    const float* b2a  = (const float*)d_in[9];
    const float* w2b  = (const float*)d_in[10];
    const float* b2b  = (const float*)d_in[11];

    int n = in_sizes[0] / 128;      // 131072 nodes
    int E = in_sizes[1] / 2;        // 2097152 edges
    int B = n / 128;                // 1024 graphs

    char* ws = (char*)d_ws;
    size_t off = 0;
    auto alloc = [&](size_t bytes) -> void* {
        void* p = ws + off;
        off = (off + bytes + 255) & ~(size_t)255;
        return p;
    };
    unsigned* h2      = (unsigned*)alloc((size_t)n * 64 * 4);           // bf16x2 rows
    int*      buckets = (int*)alloc((size_t)B * BCAP * 4);              // 12.6 MB
    int*      bcnt    = (int*)alloc((size_t)B * CSTRIDE * 4);           // 64 KB padded counters
    float*    dinv    = (float*)alloc((size_t)n * 4);
    float*    pooled  = (float*)alloc((size_t)B * 128 * 4);
    (void)ws_size; (void)n_in; (void)out_size;

    int bblk = (E + BLKB * EPTB - 1) / (BLKB * EPTB);  // 128

    hipMemsetAsync(bcnt, 0, (size_t)B * CSTRIDE * 4, stream);
    hipLaunchKernelGGL(k_bucket, dim3(bblk), dim3(BLKB), 0, stream, edge, E, B, bcnt, buckets);
    hipLaunchKernelGGL(k_deg,    dim3(B), dim3(256), 0, stream, buckets, bcnt, dinv);
    hipLaunchKernelGGL(k_gemm,   dim3(n / BM), dim3(256), 0, stream, x, W, h2);
    hipLaunchKernelGGL(k_aggr,   dim3(B), dim3(512), 0, stream, h2, buckets, bcnt, dinv, b, pooled);
    hipLaunchKernelGGL(k_mlp,    dim3(B / RB), dim3(256), 0, stream,
                       pooled, w1a, b1a, w1b, b1b, w2a, b2a, w2b, b2b, (float*)d_out, B);
}